// Round 1
// baseline (1282.448 us; speedup 1.0000x reference)
//
#include <hip/hip_runtime.h>
#include <hip/hip_bf16.h>
#include <math.h>

#define NN 50000
#define NE 800000
#define FE 16
#define CC 64
#define NG 512
#define NCLS 10
#define NCONV 7

struct MlpP { const float* w1; const float* b1; const float* w2; const float* b2; };
struct MlpAll { MlpP p[NCONV]; };

__device__ __forceinline__ int lowerb(const int* __restrict__ a, int n, int key) {
  int lo = 0, hi = n;
  while (lo < hi) { int m = (lo + hi) >> 1; if (a[m] < key) lo = m + 1; else hi = m; }
  return lo;
}

// ---- CSR build ----
__global__ __launch_bounds__(256) void k_hist(const int* __restrict__ ecol, int* __restrict__ cnt) {
  int e = blockIdx.x * 256 + threadIdx.x;
  if (e < NE) atomicAdd(&cnt[ecol[e]], 1);
}

__global__ __launch_bounds__(1024) void k_scan(int* __restrict__ cnt, int* __restrict__ cptr) {
  __shared__ int sc[1024];
  int t = threadIdx.x;
  const int CH = (NN + 1023) / 1024;  // 49
  int s0 = t * CH, s1 = s0 + CH;
  if (s0 > NN) s0 = NN;
  if (s1 > NN) s1 = NN;
  int sum = 0;
  for (int i = s0; i < s1; ++i) sum += cnt[i];
  sc[t] = sum;
  __syncthreads();
  for (int off = 1; off < 1024; off <<= 1) {
    int v = (t >= off) ? sc[t - off] : 0;
    __syncthreads();
    sc[t] += v;
    __syncthreads();
  }
  int run = sc[t] - sum;  // exclusive prefix
  for (int i = s0; i < s1; ++i) {
    int cv = cnt[i];
    cptr[i] = run;
    cnt[i] = run;  // becomes cursor
    run += cv;
  }
  if (t == 1023) cptr[NN] = sc[1023];
}

// ---- CSR scatter + all-7 edge MLPs fused ----
__global__ __launch_bounds__(256) void k_scatter_mlp(
    const int* __restrict__ erow, const int* __restrict__ ecol,
    const float* __restrict__ ea, int* __restrict__ cursor, int* __restrict__ csrc,
    float* __restrict__ wcsr, float* __restrict__ deg, MlpAll mw) {
  int e = blockIdx.x * 256 + threadIdx.x;
  if (e >= NE) return;
  int c = ecol[e];
  int p = atomicAdd(&cursor[c], 1);
  csrc[p] = erow[e];
  float a[16];
  const float4* ea4 = reinterpret_cast<const float4*>(ea + (size_t)e * 16);
  float4 q0 = ea4[0], q1 = ea4[1], q2 = ea4[2], q3 = ea4[3];
  a[0]=q0.x; a[1]=q0.y; a[2]=q0.z; a[3]=q0.w;
  a[4]=q1.x; a[5]=q1.y; a[6]=q1.z; a[7]=q1.w;
  a[8]=q2.x; a[9]=q2.y; a[10]=q2.z; a[11]=q2.w;
  a[12]=q3.x; a[13]=q3.y; a[14]=q3.z; a[15]=q3.w;
  #pragma unroll
  for (int j = 0; j < NCONV; ++j) {
    const float* w1 = mw.p[j].w1;
    const float* b1 = mw.p[j].b1;
    const float* w2 = mw.p[j].w2;
    float z = mw.p[j].b2[0];
    #pragma unroll
    for (int k = 0; k < 16; ++k) {
      float h = b1[k];
      #pragma unroll
      for (int m = 0; m < 16; ++m) h += a[m] * w1[k * 16 + m];
      h = h > 0.f ? h : 0.f;
      z += h * w2[k];
    }
    float wv = 1.f / (1.f + expf(-z));
    wcsr[(size_t)j * NE + p] = wv;
    atomicAdd(&deg[j * NN + c], wv);
  }
}

__global__ __launch_bounds__(256) void k_dis(float* __restrict__ deg) {
  int i = blockIdx.x * 256 + threadIdx.x;
  if (i < NCONV * NN) deg[i] = rsqrtf(deg[i] + 1.0f);  // +1 = self loop; always > 0
}

// transpose the 7 node-linear weights: lwT[j][ci][co] = lw_j[co][ci]
__global__ __launch_bounds__(256) void k_lwt(const float* __restrict__ c1, const float* __restrict__ h1,
                                             const float* __restrict__ h2, float* __restrict__ lwT) {
  int id = blockIdx.x * 256 + threadIdx.x;
  if (id >= NCONV * CC * CC) return;
  int j = id >> 12;
  int r = id & 4095;
  int co = r >> 6, ci = r & 63;
  const float* src = (j == 0) ? c1 : (j <= 3 ? h1 + (j - 1) * 4096 : h2 + (j - 4) * 4096);
  lwT[j * 4096 + ci * 64 + co] = src[co * 64 + ci];
}

// ---- BatchNorm stats: S and SS per channel ----
__global__ __launch_bounds__(256) void k_bnstat(const float* __restrict__ src, float* __restrict__ accum) {
  __shared__ float sS[256], sQ[256];
  int t = threadIdx.x;
  int c = t & 63, rg = t >> 6;
  int base = blockIdx.x * 196;
  float S = 0.f, Q = 0.f;
  for (int rr = rg; rr < 196; rr += 4) {
    int r = base + rr;
    if (r < NN) { float v = src[r * 64 + c]; S += v; Q += v * v; }
  }
  sS[t] = S; sQ[t] = Q;
  __syncthreads();
  if (t < 128) { sS[t] += sS[t + 128]; sQ[t] += sQ[t + 128]; }
  __syncthreads();
  if (t < 64) {
    atomicAdd(&accum[c], sS[t] + sS[t + 64]);
    atomicAdd(&accum[64 + c], sQ[t] + sQ[t + 64]);
  }
}

// ---- fused (BN+ReLU)? -> GEMM -> *dis : dst = f(src) @ lwT * dis[n] ----
__global__ __launch_bounds__(256) void k_gemm(const float* __restrict__ src, const float* __restrict__ lwT,
                                              const float* __restrict__ accum, const float* __restrict__ dis,
                                              float* __restrict__ dst, int useBN) {
  __shared__ float xs[64 * 65];
  int t = threadIdx.x;
  int rows0 = blockIdx.x * 64;
  // stage 64 rows, fused BN+ReLU
  for (int i = 0; i < 16; ++i) {
    int g = t + i * 256;
    int r = g >> 6, ci = g & 63;
    int row = rows0 + r;
    float v = 0.f;
    if (row < NN) v = src[row * 64 + ci];
    if (useBN) {
      float S = accum[ci], SS = accum[64 + ci];
      float mu = S * (1.0f / NN);
      float var = SS * (1.0f / NN) - mu * mu;
      var = var < 0.f ? 0.f : var;
      float rs = rsqrtf(var + 1e-5f);
      v = (v - mu) * rs;
      v = v > 0.f ? v : 0.f;
    }
    xs[r * 65 + ci] = v;
  }
  __syncthreads();
  int lane = t & 63;
  int cobase = __builtin_amdgcn_readfirstlane((t >> 6) << 4);  // wave-uniform -> scalar weight loads
  float acc[16];
  #pragma unroll
  for (int u = 0; u < 16; ++u) acc[u] = 0.f;
  #pragma unroll 8
  for (int ci = 0; ci < 64; ++ci) {
    float xv = xs[lane * 65 + ci];
    const float* wrow = lwT + ci * 64 + cobase;
    #pragma unroll
    for (int u = 0; u < 16; ++u) acc[u] += xv * wrow[u];
  }
  __syncthreads();
  int row = rows0 + lane;
  float d = (row < NN) ? dis[row] : 0.f;
  #pragma unroll
  for (int u = 0; u < 16; ++u) xs[lane * 65 + cobase + u] = acc[u] * d;
  __syncthreads();
  for (int i = 0; i < 16; ++i) {
    int g = t + i * 256;
    int r = g >> 6, co = g & 63;
    int orow = rows0 + r;
    if (orow < NN) dst[orow * 64 + co] = xs[r * 65 + co];
  }
}

// ---- aggregation: wave per node, lane = channel; epilogue fuses skip adds ----
// mode 0: out = v ; mode 1: s=v+skipA -> out=s, outX1=s ; mode 2: out = relu(v+skipA+skipX1)
__global__ __launch_bounds__(256) void k_agg(const float* __restrict__ T, const float* __restrict__ wcsr,
                                             const int* __restrict__ csrc, const int* __restrict__ cptr,
                                             const float* __restrict__ dis, float* __restrict__ out,
                                             const float* __restrict__ skipA, const float* __restrict__ skipX1,
                                             float* __restrict__ outX1, int mode) {
  int t = threadIdx.x;
  int n = blockIdx.x * 4 + (t >> 6);
  if (n >= NN) return;
  int lane = t & 63;
  int lo = cptr[n], hi = cptr[n + 1];
  float acc = T[n * 64 + lane];  // self loop (xls already has dis[n] folded in)
  for (int k = lo; k < hi; ++k) {
    float w = wcsr[k];
    int s = csrc[k];
    acc += w * T[s * 64 + lane];
  }
  float v = dis[n] * acc;
  int idx = n * 64 + lane;
  if (mode == 1) {
    float sv = v + skipA[idx];
    out[idx] = sv;
    outX1[idx] = sv;
  } else if (mode == 2) {
    float sv = v + skipA[idx] + skipX1[idx];
    out[idx] = sv > 0.f ? sv : 0.f;
  } else {
    out[idx] = v;
  }
}

// ---- global max pool over sorted batch (binary search bounds) ----
__global__ void k_pool(const float* __restrict__ x2, const int* __restrict__ batch, float* __restrict__ pooled) {
  int g = blockIdx.x;
  int c = threadIdx.x;  // 64 threads = 1 wave
  int lo = lowerb(batch, NN, g);
  int hi = lowerb(batch, NN, g + 1);
  float m = -INFINITY;
  for (int n = lo; n < hi; ++n) m = fmaxf(m, x2[n * 64 + c]);
  pooled[g * 64 + c] = m;
}

__global__ __launch_bounds__(256) void k_cls(const float* __restrict__ pooled, const float* __restrict__ lw,
                                             const float* __restrict__ lb, float* __restrict__ out) {
  int id = blockIdx.x * 256 + threadIdx.x;
  if (id >= NG * NCLS) return;
  int g = id / NCLS, k = id % NCLS;
  float acc = lb[k];
  #pragma unroll 8
  for (int c = 0; c < 64; ++c) acc += pooled[g * 64 + c] * lw[k * 64 + c];
  out[id] = acc;
}

extern "C" void kernel_launch(void* const* d_in, const int* in_sizes, int n_in,
                              void* d_out, int out_size, void* d_ws, size_t ws_size,
                              hipStream_t stream) {
  (void)in_sizes; (void)n_in; (void)out_size; (void)ws_size;
  const float* x     = (const float*)d_in[0];
  const int*   ei    = (const int*)d_in[1];
  const int*   batch = (const int*)d_in[2];
  // d_in[3] = dropout (0) -- unused
  const float* ea    = (const float*)d_in[4];
  const float* c1_lw = (const float*)d_in[5];
  const float* c1_w1 = (const float*)d_in[6];
  const float* c1_b1 = (const float*)d_in[7];
  const float* c1_w2 = (const float*)d_in[8];
  const float* c1_b2 = (const float*)d_in[9];
  const float* h1_lw = (const float*)d_in[10];
  const float* h1_w1 = (const float*)d_in[11];
  const float* h1_b1 = (const float*)d_in[12];
  const float* h1_w2 = (const float*)d_in[13];
  const float* h1_b2 = (const float*)d_in[14];
  const float* h2_lw = (const float*)d_in[15];
  const float* h2_w1 = (const float*)d_in[16];
  const float* h2_b1 = (const float*)d_in[17];
  const float* h2_w2 = (const float*)d_in[18];
  const float* h2_b2 = (const float*)d_in[19];
  const float* lin_w = (const float*)d_in[20];
  const float* lin_b = (const float*)d_in[21];
  float* out = (float*)d_out;

  char* base = (char*)d_ws;
  size_t off = 0;
  auto alloc = [&](size_t bytes) -> size_t {
    size_t o = off;
    off = (off + bytes + 255) & ~(size_t)255;
    return o;
  };
  size_t o_wcsr   = alloc((size_t)NCONV * NE * 4);
  size_t o_csrc   = alloc((size_t)NE * 4);
  size_t o_cptr   = alloc((size_t)(NN + 1) * 4);
  size_t o_cursor = alloc((size_t)NN * 4);         // zeroed region starts here
  size_t o_deg    = alloc((size_t)NCONV * NN * 4);
  size_t o_accum  = alloc((size_t)6 * 128 * 4);
  size_t o_lwt    = alloc((size_t)NCONV * 4096 * 4);  // zeroed region ends before here
  size_t o_T      = alloc((size_t)NN * 64 * 4);
  size_t o_A      = alloc((size_t)NN * 64 * 4);
  size_t o_B      = alloc((size_t)NN * 64 * 4);
  size_t o_X1     = alloc((size_t)NN * 64 * 4);
  size_t o_pool   = alloc((size_t)NG * 64 * 4);

  float* wcsr   = (float*)(base + o_wcsr);
  int*   csrc   = (int*)(base + o_csrc);
  int*   cptr   = (int*)(base + o_cptr);
  int*   cursor = (int*)(base + o_cursor);
  float* deg    = (float*)(base + o_deg);
  float* accum  = (float*)(base + o_accum);
  float* lwt    = (float*)(base + o_lwt);
  float* T      = (float*)(base + o_T);
  float* A      = (float*)(base + o_A);
  float* B      = (float*)(base + o_B);
  float* X1     = (float*)(base + o_X1);
  float* pooled = (float*)(base + o_pool);

  // one memset covers cursor + deg + accum (contiguous)
  hipMemsetAsync(base + o_cursor, 0, o_lwt - o_cursor, stream);

  const int* erow = ei;
  const int* ecol = ei + NE;

  k_hist<<<(NE + 255) / 256, 256, 0, stream>>>(ecol, cursor);
  k_scan<<<1, 1024, 0, stream>>>(cursor, cptr);

  MlpAll mw;
  mw.p[0] = {c1_w1, c1_b1, c1_w2, c1_b2};
  for (int i = 0; i < 3; ++i) {
    mw.p[1 + i] = {h1_w1 + i * 256, h1_b1 + i * 16, h1_w2 + i * 16, h1_b2 + i};
    mw.p[4 + i] = {h2_w1 + i * 256, h2_b1 + i * 16, h2_w2 + i * 16, h2_b2 + i};
  }
  k_scatter_mlp<<<(NE + 255) / 256, 256, 0, stream>>>(erow, ecol, ea, cursor, csrc, wcsr, deg, mw);
  k_dis<<<(NCONV * NN + 255) / 256, 256, 0, stream>>>(deg);
  k_lwt<<<(NCONV * 4096) / 256, 256, 0, stream>>>(c1_lw, h1_lw, h2_lw, lwt);

  const int GB = (NN + 63) / 64;  // 782
  const int AB = (NN + 3) / 4;    // 12500

  // conv1 -> A (= x0)
  k_gemm<<<GB, 256, 0, stream>>>(x, lwt, nullptr, deg, T, 0);
  k_agg<<<AB, 256, 0, stream>>>(T, wcsr, csrc, cptr, deg, A, nullptr, nullptr, nullptr, 0);

  // hidden loop 1: x = conv(relu(BN(x))); after i==2 fuse x1 = x + x0
  for (int i = 0; i < 3; ++i) {
    const float* src = (i == 0) ? A : B;
    k_bnstat<<<256, 256, 0, stream>>>(src, accum + i * 128);
    k_gemm<<<GB, 256, 0, stream>>>(src, lwt + (1 + i) * 4096, accum + i * 128,
                                   deg + (size_t)(1 + i) * NN, T, 1);
    int mode = (i == 2) ? 1 : 0;
    k_agg<<<AB, 256, 0, stream>>>(T, wcsr + (size_t)(1 + i) * NE, csrc, cptr,
                                  deg + (size_t)(1 + i) * NN, B, A, nullptr, X1, mode);
  }
  // hidden loop 2; after i==2 fuse x2 = relu(x + x0 + x1)
  for (int i = 0; i < 3; ++i) {
    k_bnstat<<<256, 256, 0, stream>>>(B, accum + (3 + i) * 128);
    k_gemm<<<GB, 256, 0, stream>>>(B, lwt + (4 + i) * 4096, accum + (3 + i) * 128,
                                   deg + (size_t)(4 + i) * NN, T, 1);
    int mode = (i == 2) ? 2 : 0;
    k_agg<<<AB, 256, 0, stream>>>(T, wcsr + (size_t)(4 + i) * NE, csrc, cptr,
                                  deg + (size_t)(4 + i) * NN, B, A, X1, nullptr, mode);
  }

  k_pool<<<NG, 64, 0, stream>>>(B, batch, pooled);
  k_cls<<<(NG * NCLS + 255) / 256, 256, 0, stream>>>(pooled, lin_w, lin_b, out);
}